// Round 7
// baseline (2705.525 us; speedup 1.0000x reference)
//
#include <hip/hip_runtime.h>
#include <hip/hip_fp16.h>

#define B_   32
#define S_   256
#define EMB_ 512
#define H_   1024
#define G4_  4096
#define NL_  5
#define NBLK 64
#define NW   16

typedef short bf16x8 __attribute__((ext_vector_type(8)));
typedef float f32x4 __attribute__((ext_vector_type(4)));
typedef unsigned long long ull;

__device__ inline unsigned short f2bf(float x) {
  unsigned u = __float_as_uint(x);
  return (unsigned short)((u + 0x7FFF + ((u >> 16) & 1)) >> 16);
}
__device__ inline float bf2f(unsigned short b) {
  return __uint_as_float(((unsigned)b) << 16);
}
__device__ inline ull ldq(const ull* p) {
  return __hip_atomic_load(p, __ATOMIC_RELAXED, __HIP_MEMORY_SCOPE_AGENT);
}
__device__ inline void stw(unsigned* p, unsigned v) {
  __hip_atomic_store(p, v, __ATOMIC_RELAXED, __HIP_MEMORY_SCOPE_AGENT);
}

// ---------------------------------------------------------------------------
// K0: transpose U [1024][4096] -> Ut [4096][1024].
__global__ __launch_bounds__(256) void k_transpose(const float* __restrict__ U,
                                                   float* __restrict__ Ut) {
  __shared__ float tile[32][33];
  int c0 = blockIdx.x * 32, k0 = blockIdx.y * 32;
  int tx = threadIdx.x & 31, ty = threadIdx.x >> 5;
#pragma unroll
  for (int i = 0; i < 4; ++i)
    tile[ty + 8 * i][tx] = U[(size_t)(k0 + ty + 8 * i) * G4_ + c0 + tx];
  __syncthreads();
#pragma unroll
  for (int i = 0; i < 4; ++i)
    Ut[(size_t)(c0 + ty + 8 * i) * H_ + k0 + tx] = tile[tx][ty + 8 * i];
}

// ---------------------------------------------------------------------------
// K0b: build MFMA-ready B-fragments of U, split bf16 hi/lo. (proven layout)
__global__ __launch_bounds__(256) void k_prep(const float* __restrict__ Ut,
                                              bf16x8* __restrict__ Ubf) {
  int gid = blockIdx.x * 256 + threadIdx.x;
  int l = gid & 63;
  int bxws = gid >> 6;
  int n = l & 15, kgrp = l >> 4;
  int s = bxws & 7, bw = bxws >> 3;
  int w = bw & 3, bx = bw >> 2;
  int g = n & 3, ju = n >> 2;
  int gcol = g * 1024 + bx * 4 + ju;
  int kbase = w * 256 + s * 32 + kgrp * 8;
  const float4* f = (const float4*)(Ut + (size_t)gcol * H_ + kbase);
  float4 f0 = f[0], f1 = f[1];
  float v[8] = {f0.x, f0.y, f0.z, f0.w, f1.x, f1.y, f1.z, f1.w};
  bf16x8 vh, vl;
#pragma unroll
  for (int j = 0; j < 8; ++j) {
    unsigned short hi = f2bf(v[j]);
    vh[j] = (short)hi;
    vl[j] = (short)f2bf(v[j] - bf2f(hi));
  }
  Ubf[(size_t)bxws * 128 + l] = vh;
  Ubf[(size_t)bxws * 128 + 64 + l] = vl;
}

// ---------------------------------------------------------------------------
// K1: xz (unchanged — known good)
__global__ __launch_bounds__(256) void k_xw(const int* __restrict__ tokens,
                                            const float* __restrict__ emb,
                                            const float* __restrict__ W,
                                            const float* __restrict__ bias,
                                            unsigned short* __restrict__ xz) {
  __shared__ int tok_s[32];
  __shared__ float A_lds[32 * 36];
  __shared__ float B_lds[32 * 128];
  __shared__ unsigned short zout[128 * 40];

  int s = blockIdx.y;
  int c0 = blockIdx.x * 128;
  int tid = threadIdx.x;
  if (tid < 32) tok_s[tid] = tokens[tid * S_ + s];

  int tc = tid & 31, tb = tid >> 5;
  int ar = tid >> 3, ap = tid & 7;

  float acc[4][4];
#pragma unroll
  for (int i = 0; i < 4; ++i)
#pragma unroll
    for (int j = 0; j < 4; ++j) acc[i][j] = 0.f;

  for (int kb = 0; kb < 16; ++kb) {
    int k0 = kb * 32;
    __syncthreads();
    {
      const float4 av = *(const float4*)(emb + (size_t)tok_s[ar] * EMB_ + k0 + ap * 4);
      A_lds[(ap * 4 + 0) * 36 + ar] = av.x;
      A_lds[(ap * 4 + 1) * 36 + ar] = av.y;
      A_lds[(ap * 4 + 2) * 36 + ar] = av.z;
      A_lds[(ap * 4 + 3) * 36 + ar] = av.w;
    }
#pragma unroll
    for (int i = 0; i < 4; ++i) {
      int kk = tb + 8 * i;
      float4 bv = *(const float4*)(W + (size_t)(k0 + kk) * G4_ + c0 + 4 * tc);
      *(float4*)(&B_lds[kk * 128 + 4 * tc]) = bv;
    }
    __syncthreads();
#pragma unroll
    for (int kk = 0; kk < 32; ++kk) {
      float a0 = A_lds[kk * 36 + tb];
      float a1 = A_lds[kk * 36 + tb + 8];
      float a2 = A_lds[kk * 36 + tb + 16];
      float a3 = A_lds[kk * 36 + tb + 24];
      float b0 = B_lds[kk * 128 + tc];
      float b1 = B_lds[kk * 128 + tc + 32];
      float b2 = B_lds[kk * 128 + tc + 64];
      float b3 = B_lds[kk * 128 + tc + 96];
      acc[0][0] += a0 * b0; acc[0][1] += a1 * b0; acc[0][2] += a2 * b0; acc[0][3] += a3 * b0;
      acc[1][0] += a0 * b1; acc[1][1] += a1 * b1; acc[1][2] += a2 * b1; acc[1][3] += a3 * b1;
      acc[2][0] += a0 * b2; acc[2][1] += a1 * b2; acc[2][2] += a2 * b2; acc[2][3] += a3 * b2;
      acc[3][0] += a0 * b3; acc[3][1] += a1 * b3; acc[3][2] += a2 * b3; acc[3][3] += a3 * b3;
    }
  }
  __syncthreads();
#pragma unroll
  for (int qc = 0; qc < 4; ++qc) {
    float bv = bias[c0 + tc + 32 * qc];
#pragma unroll
    for (int qb = 0; qb < 4; ++qb) {
      float v = acc[qc][qb] + bv;
      zout[(tc + 32 * qc) * 40 + tb + 8 * qb] = __half_as_ushort(__float2half_rn(v));
    }
  }
  __syncthreads();
  {
    int cc = tid >> 1, hh = (tid & 1) * 16;
    uint4 v0 = *(const uint4*)(&zout[cc * 40 + hh]);
    uint4 v1 = *(const uint4*)(&zout[cc * 40 + hh + 8]);
    unsigned short* dst = xz + ((size_t)s * G4_ + c0 + cc) * 32 + hh;
    *(uint4*)(dst) = v0;
    *(uint4*)(dst + 8) = v1;
  }
}

// ---------------------------------------------------------------------------
// K2: persistent steps v4. grid 64 x 1024 (16 waves). Block bx = 16 units;
// wave w = K-slice [w*64,(w+1)*64) -> U regs only 64 VGPR/thread (resident).
// Sync: per-producer flags. Block p stores flg[p]=t+1 after writing its h_t
// slice; wave w polls only its 4 producer blocks (units w*64..w*64+63 are
// owned by blocks w*4..w*4+3). All A loads issued up-front (one LLC latency).
__global__ __launch_bounds__(1024, 4) void k_steps4(
    const bf16x8* __restrict__ Ubf,
    const unsigned short* __restrict__ xz,
    unsigned* __restrict__ Hh0, unsigned* __restrict__ Hl0,
    unsigned* __restrict__ Hh1, unsigned* __restrict__ Hl1,
    unsigned* __restrict__ flg) {
  __shared__ float red[NW * 8 * 256];   // 128 KB: slot = w*8 + m*4 + cg
  __shared__ float zg[32 * 66];         // [b][cg*16+n16]

  const int tid = threadIdx.x;
  const int bx = blockIdx.x;
  const int l = tid & 63, w = tid >> 6;   // w in 0..15

  // U frags resident: wave w covers kidx8 [w*8, w*8+8): kslice=w>>2, s8=(w&3)*2+s
  bf16x8 uh[4][2], ul[4][2];
#pragma unroll
  for (int cg = 0; cg < 4; ++cg) {
#pragma unroll
    for (int s = 0; s < 2; ++s) {
      size_t fi = ((size_t)(bx * 4 + cg) * 4 + (w >> 2)) * 8 + (w & 3) * 2 + s;
      uh[cg][s] = Ubf[fi * 128 + l];
      ul[cg][s] = Ubf[fi * 128 + 64 + l];
    }
  }

  // reducer mapping: tid -> (zm, zpos, zch); covers 2 cg = zch*2+{0,1}
  const int zm = tid >> 9, zpos = (tid >> 1) & 255, zch = tid & 1;
  const int zl = zpos >> 2, zr = zpos & 3;
  const int zn16 = zl & 15;
  const int zb = zm * 16 + (zl >> 4) * 4 + zr;
  int zgcol[2];
#pragma unroll
  for (int q = 0; q < 2; ++q)
    zgcol[q] = (zn16 & 3) * 1024 + (bx * 4 + zch * 2 + q) * 4 + (zn16 >> 2);

  // gate mapping (tid<512): batch gb, unit gu; h-store word index
  const int gb = tid & 31, gu = tid >> 5;
  const int gk = bx * 16 + gu;
  const int widx = (gb >> 4) * 8192 + (gk >> 3) * 64 + (gb & 15) * 4 + ((gk & 7) >> 1);
  const int zrd = gb * 66 + (gu >> 2) * 16 + (gu & 3) * 4;
  float creg = 0.f;

  const unsigned* myflg = flg + (w * 4 + (l & 3)) * 32;   // 4 producers/wave

  for (int t = 0; t < S_; ++t) {
    const ull* RdH = (const ull*)((t & 1) ? Hh0 : Hh1);
    const ull* RdL = (const ull*)((t & 1) ? Hl0 : Hl1);
    unsigned* WrH = (t & 1) ? Hh1 : Hh0;
    unsigned* WrL = (t & 1) ? Hl1 : Hl0;

    // xz prefetch (independent of h)
    float xzv[2];
#pragma unroll
    for (int q = 0; q < 2; ++q)
      xzv[q] = __half2float(__ushort_as_half(xz[((size_t)t * G4_ + zgcol[q]) * 32 + zb]));

    if (t > 0) {
      // per-wave poll of this wave's 4 producer blocks
      while (true) {
        unsigned v = __hip_atomic_load(myflg, __ATOMIC_RELAXED, __HIP_MEMORY_SCOPE_AGENT);
        if (__all((int)(v >= (unsigned)t))) break;
        __builtin_amdgcn_s_sleep(1);
      }

      // issue ALL fragment loads up-front (2 stages x 4 frags x 2 ldq)
      union F { ull q[2]; bf16x8 v; };
      F A[2][4];
#pragma unroll
      for (int s = 0; s < 2; ++s) {
        int i0 = ((w * 8 + s * 4) * 32) + l * 2;
        A[s][0].q[0] = ldq(RdH + i0);        A[s][0].q[1] = ldq(RdH + i0 + 1);
        A[s][1].q[0] = ldq(RdH + 4096 + i0); A[s][1].q[1] = ldq(RdH + 4096 + i0 + 1);
        A[s][2].q[0] = ldq(RdL + i0);        A[s][2].q[1] = ldq(RdL + i0 + 1);
        A[s][3].q[0] = ldq(RdL + 4096 + i0); A[s][3].q[1] = ldq(RdL + 4096 + i0 + 1);
      }

      f32x4 acc[4][2];
#pragma unroll
      for (int cg = 0; cg < 4; ++cg) {
        acc[cg][0] = (f32x4){0.f, 0.f, 0.f, 0.f};
        acc[cg][1] = (f32x4){0.f, 0.f, 0.f, 0.f};
      }
#pragma unroll
      for (int s = 0; s < 2; ++s) {
#pragma unroll
        for (int cg = 0; cg < 4; ++cg) {
          acc[cg][0] = __builtin_amdgcn_mfma_f32_16x16x32_bf16(A[s][0].v, uh[cg][s], acc[cg][0], 0, 0, 0);
          acc[cg][1] = __builtin_amdgcn_mfma_f32_16x16x32_bf16(A[s][1].v, uh[cg][s], acc[cg][1], 0, 0, 0);
          acc[cg][0] = __builtin_amdgcn_mfma_f32_16x16x32_bf16(A[s][2].v, uh[cg][s], acc[cg][0], 0, 0, 0);
          acc[cg][1] = __builtin_amdgcn_mfma_f32_16x16x32_bf16(A[s][3].v, uh[cg][s], acc[cg][1], 0, 0, 0);
          acc[cg][0] = __builtin_amdgcn_mfma_f32_16x16x32_bf16(A[s][0].v, ul[cg][s], acc[cg][0], 0, 0, 0);
          acc[cg][1] = __builtin_amdgcn_mfma_f32_16x16x32_bf16(A[s][1].v, ul[cg][s], acc[cg][1], 0, 0, 0);
        }
      }
#pragma unroll
      for (int cg = 0; cg < 4; ++cg) {
        *(f32x4*)(&red[(w * 8 + 0 * 4 + cg) * 256 + l * 4]) = acc[cg][0];
        *(f32x4*)(&red[(w * 8 + 1 * 4 + cg) * 256 + l * 4]) = acc[cg][1];
      }
    }
    __syncthreads();

    // reduce 16 wave-partials + xz -> zg
#pragma unroll
    for (int q = 0; q < 2; ++q) {
      int cg = zch * 2 + q;
      float zz = xzv[q];
      if (t > 0) {
#pragma unroll
        for (int ww = 0; ww < NW; ++ww)
          zz += red[(ww * 8 + zm * 4 + cg) * 256 + zpos];
      }
      zg[zb * 66 + cg * 16 + zn16] = zz;
    }
    __syncthreads();

    // gates: tid<512, one (b, unit) each
    if (tid < 512) {
      float zi = zg[zrd + 0];
      float zf = zg[zrd + 1];
      float zc_ = zg[zrd + 2];
      float zo = zg[zrd + 3];
      float ig = 1.f / (1.f + __expf(-zi));
      float fg = 1.f / (1.f + __expf(-zf));
      float gg = tanhf(zc_);
      float og = 1.f / (1.f + __expf(-zo));
      creg = fg * creg + ig * gg;
      float hv = og * tanhf(creg);
      unsigned short hh_ = f2bf(hv);
      unsigned short hl_ = f2bf(hv - bf2f(hh_));
      unsigned pk = (unsigned)hh_ | ((unsigned)hl_ << 16);
      unsigned other = (unsigned)__shfl_xor((int)pk, 32, 64);   // partner unit gu^1
      if ((gu & 1) == 0)
        stw(WrH + widx, (pk & 0xffffu) | (other << 16));
      else
        stw(WrL + widx, (other >> 16) | (pk & 0xffff0000u));
    }
    __syncthreads();   // every wave's vmcnt drained -> block's h slice at LLC
    if (tid == 0)
      stw(flg + bx * 32, (unsigned)(t + 1));
  }
}

// ---------------------------------------------------------------------------
// K3: logits from fragment-layout h. grid 5, block 256.
__global__ __launch_bounds__(256) void k_head4(const unsigned* __restrict__ Hh,
                                               const unsigned* __restrict__ Hl,
                                               const float* __restrict__ Wd,
                                               const float* __restrict__ bd,
                                               float* __restrict__ out) {
  __shared__ float red[32 * 9];
  int lbl = blockIdx.x;
  int tid = threadIdx.x;
  int b = tid >> 3, ks = tid & 7;
  int mb = (b >> 4) * 8192 + (b & 15) * 4;
  float acc = 0.f;
  for (int k = ks * 128; k < ks * 128 + 128; ++k) {
    int idx = mb + (k >> 3) * 64 + ((k & 7) >> 1);
    int sh = (k & 1) * 16;
    float hv = bf2f((unsigned short)((Hh[idx] >> sh) & 0xffffu)) +
               bf2f((unsigned short)((Hl[idx] >> sh) & 0xffffu));
    acc += hv * Wd[k * NL_ + lbl];
  }
  red[b * 9 + ks] = acc;
  __syncthreads();
  if (tid < 32) {
    float s = bd[lbl];
#pragma unroll
    for (int i = 0; i < 8; ++i) s += red[tid * 9 + i];
    out[tid * NL_ + lbl] = s;
  }
}

// ---------------------------------------------------------------------------
extern "C" void kernel_launch(void* const* d_in, const int* in_sizes, int n_in,
                              void* d_out, int out_size, void* d_ws, size_t ws_size,
                              hipStream_t stream) {
  const int* tokens  = (const int*)d_in[0];
  const float* emb   = (const float*)d_in[1];
  const float* W     = (const float*)d_in[2];
  const float* U     = (const float*)d_in[3];
  const float* bias  = (const float*)d_in[4];
  const float* Wd    = (const float*)d_in[5];
  const float* bd    = (const float*)d_in[6];
  float* out = (float*)d_out;

  char* ws = (char*)d_ws;
  // Overlaid layout:
  //   Ut fp32 [4096][1024]   @ 0          (16 MB, dead after k_prep)
  //   xz fp16 [256][4096][32] @ 0         (64 MB, written by k_xw after k_prep)
  //   Ubf bf16 frags         @ 67,108,864 (16 MB)
  //   frag-layout h planes: Hh0,Hl0,Hh1,Hl1 (64 KB each) @ 83,886,080
  //   flg                    @ 84,148,224 (8 KB: 64 flags, 128B apart)
  float* Ut          = (float*)ws;
  unsigned short* xz = (unsigned short*)ws;
  bf16x8* Ubf        = (bf16x8*)(ws + 67108864);
  unsigned* Hh0      = (unsigned*)(ws + 83886080);
  unsigned* Hl0      = (unsigned*)(ws + 83886080 + 65536);
  unsigned* Hh1      = (unsigned*)(ws + 83886080 + 131072);
  unsigned* Hl1      = (unsigned*)(ws + 83886080 + 196608);
  unsigned* flg      = (unsigned*)(ws + 84148224);

  hipMemsetAsync(flg, 0, 8192, stream);
  k_transpose<<<dim3(128, 32), 256, 0, stream>>>(U, Ut);
  k_prep<<<2048, 256, 0, stream>>>(Ut, Ubf);
  k_xw<<<dim3(32, 256), 256, 0, stream>>>(tokens, emb, W, bias, xz);  // clobbers Ut (dead)

  k_steps4<<<NBLK, 1024, 0, stream>>>(Ubf, xz, Hh0, Hl0, Hh1, Hl1, flg);

  // t=255 (odd) wrote buf1
  k_head4<<<NL_, 256, 0, stream>>>(Hh1, Hl1, Wd, bd, out);
}

// Round 8
// 1748.015 us; speedup vs baseline: 1.5478x; 1.5478x over previous
//
#include <hip/hip_runtime.h>
#include <hip/hip_fp16.h>

#define B_   32
#define S_   256
#define EMB_ 512
#define H_   1024
#define G4_  4096
#define NL_  5
#define NBLK 128

typedef short bf16x8 __attribute__((ext_vector_type(8)));
typedef float f32x4 __attribute__((ext_vector_type(4)));
typedef unsigned long long ull;

__device__ inline unsigned short f2bf(float x) {
  unsigned u = __float_as_uint(x);
  return (unsigned short)((u + 0x7FFF + ((u >> 16) & 1)) >> 16);
}
__device__ inline float bf2f(unsigned short b) {
  return __uint_as_float(((unsigned)b) << 16);
}
__device__ inline ull ldq(const ull* p) {
  return __hip_atomic_load(p, __ATOMIC_RELAXED, __HIP_MEMORY_SCOPE_AGENT);
}
__device__ inline void stw(unsigned* p, unsigned v) {
  __hip_atomic_store(p, v, __ATOMIC_RELAXED, __HIP_MEMORY_SCOPE_AGENT);
}

// ---------------------------------------------------------------------------
// K0: transpose U [1024][4096] -> Ut [4096][1024].
__global__ __launch_bounds__(256) void k_transpose(const float* __restrict__ U,
                                                   float* __restrict__ Ut) {
  __shared__ float tile[32][33];
  int c0 = blockIdx.x * 32, k0 = blockIdx.y * 32;
  int tx = threadIdx.x & 31, ty = threadIdx.x >> 5;
#pragma unroll
  for (int i = 0; i < 4; ++i)
    tile[ty + 8 * i][tx] = U[(size_t)(k0 + ty + 8 * i) * G4_ + c0 + tx];
  __syncthreads();
#pragma unroll
  for (int i = 0; i < 4; ++i)
    Ut[(size_t)(c0 + ty + 8 * i) * H_ + k0 + tx] = tile[tx][ty + 8 * i];
}

// ---------------------------------------------------------------------------
// K0b: build MFMA-ready B-fragments of U, split bf16 hi/lo. (proven layout)
// Ubf[((ug*4 + ks)*8 + s8)*128 + plane*64 + l]: value U[k][gcol],
// k = ks*256 + s8*32 + (l>>4)*8 + j, n16 = l&15,
// gcol = (n16&3)*1024 + ug*4 + (n16>>2).
__global__ __launch_bounds__(256) void k_prep(const float* __restrict__ Ut,
                                              bf16x8* __restrict__ Ubf) {
  int gid = blockIdx.x * 256 + threadIdx.x;
  int l = gid & 63;
  int bxws = gid >> 6;
  int n = l & 15, kgrp = l >> 4;
  int s = bxws & 7, bw = bxws >> 3;
  int w = bw & 3, bx = bw >> 2;
  int g = n & 3, ju = n >> 2;
  int gcol = g * 1024 + bx * 4 + ju;
  int kbase = w * 256 + s * 32 + kgrp * 8;
  const float4* f = (const float4*)(Ut + (size_t)gcol * H_ + kbase);
  float4 f0 = f[0], f1 = f[1];
  float v[8] = {f0.x, f0.y, f0.z, f0.w, f1.x, f1.y, f1.z, f1.w};
  bf16x8 vh, vl;
#pragma unroll
  for (int j = 0; j < 8; ++j) {
    unsigned short hi = f2bf(v[j]);
    vh[j] = (short)hi;
    vl[j] = (short)f2bf(v[j] - bf2f(hi));
  }
  Ubf[(size_t)bxws * 128 + l] = vh;
  Ubf[(size_t)bxws * 128 + 64 + l] = vl;
}

// ---------------------------------------------------------------------------
// K1: xz (unchanged — known good)
__global__ __launch_bounds__(256) void k_xw(const int* __restrict__ tokens,
                                            const float* __restrict__ emb,
                                            const float* __restrict__ W,
                                            const float* __restrict__ bias,
                                            unsigned short* __restrict__ xz) {
  __shared__ int tok_s[32];
  __shared__ float A_lds[32 * 36];
  __shared__ float B_lds[32 * 128];
  __shared__ unsigned short zout[128 * 40];

  int s = blockIdx.y;
  int c0 = blockIdx.x * 128;
  int tid = threadIdx.x;
  if (tid < 32) tok_s[tid] = tokens[tid * S_ + s];

  int tc = tid & 31, tb = tid >> 5;
  int ar = tid >> 3, ap = tid & 7;

  float acc[4][4];
#pragma unroll
  for (int i = 0; i < 4; ++i)
#pragma unroll
    for (int j = 0; j < 4; ++j) acc[i][j] = 0.f;

  for (int kb = 0; kb < 16; ++kb) {
    int k0 = kb * 32;
    __syncthreads();
    {
      const float4 av = *(const float4*)(emb + (size_t)tok_s[ar] * EMB_ + k0 + ap * 4);
      A_lds[(ap * 4 + 0) * 36 + ar] = av.x;
      A_lds[(ap * 4 + 1) * 36 + ar] = av.y;
      A_lds[(ap * 4 + 2) * 36 + ar] = av.z;
      A_lds[(ap * 4 + 3) * 36 + ar] = av.w;
    }
#pragma unroll
    for (int i = 0; i < 4; ++i) {
      int kk = tb + 8 * i;
      float4 bv = *(const float4*)(W + (size_t)(k0 + kk) * G4_ + c0 + 4 * tc);
      *(float4*)(&B_lds[kk * 128 + 4 * tc]) = bv;
    }
    __syncthreads();
#pragma unroll
    for (int kk = 0; kk < 32; ++kk) {
      float a0 = A_lds[kk * 36 + tb];
      float a1 = A_lds[kk * 36 + tb + 8];
      float a2 = A_lds[kk * 36 + tb + 16];
      float a3 = A_lds[kk * 36 + tb + 24];
      float b0 = B_lds[kk * 128 + tc];
      float b1 = B_lds[kk * 128 + tc + 32];
      float b2 = B_lds[kk * 128 + tc + 64];
      float b3 = B_lds[kk * 128 + tc + 96];
      acc[0][0] += a0 * b0; acc[0][1] += a1 * b0; acc[0][2] += a2 * b0; acc[0][3] += a3 * b0;
      acc[1][0] += a0 * b1; acc[1][1] += a1 * b1; acc[1][2] += a2 * b1; acc[1][3] += a3 * b1;
      acc[2][0] += a0 * b2; acc[2][1] += a1 * b2; acc[2][2] += a2 * b2; acc[2][3] += a3 * b2;
      acc[3][0] += a0 * b3; acc[3][1] += a1 * b3; acc[3][2] += a2 * b3; acc[3][3] += a3 * b3;
    }
  }
  __syncthreads();
#pragma unroll
  for (int qc = 0; qc < 4; ++qc) {
    float bv = bias[c0 + tc + 32 * qc];
#pragma unroll
    for (int qb = 0; qb < 4; ++qb) {
      float v = acc[qc][qb] + bv;
      zout[(tc + 32 * qc) * 40 + tb + 8 * qb] = __half_as_ushort(__float2half_rn(v));
    }
  }
  __syncthreads();
  {
    int cc = tid >> 1, hh = (tid & 1) * 16;
    uint4 v0 = *(const uint4*)(&zout[cc * 40 + hh]);
    uint4 v1 = *(const uint4*)(&zout[cc * 40 + hh + 8]);
    unsigned short* dst = xz + ((size_t)s * G4_ + c0 + cc) * 32 + hh;
    *(uint4*)(dst) = v0;
    *(uint4*)(dst + 8) = v1;
  }
}

// ---------------------------------------------------------------------------
// K2: persistent steps v5. grid 128 x 512 (8 waves). Block bx owns 8 units
// (unit-groups 2bx, 2bx+1 = 32 gate cols). Wave w = K-slice [w*128,(w+1)*128).
// U slice (128 KB) staged in LDS ONCE — no per-step refetch, by construction.
// h in A-fragment layout at LLC (relaxed AGENT atomics), per-producer flags.
__global__ __launch_bounds__(512, 2) void k_steps5(
    const bf16x8* __restrict__ Ubf,
    const unsigned short* __restrict__ xz,
    unsigned* __restrict__ Hh0, unsigned* __restrict__ Hl0,
    unsigned* __restrict__ Hh1, unsigned* __restrict__ Hl1,
    unsigned* __restrict__ flg) {
  __shared__ bf16x8 UL[8192];     // 128 KB: ((cg*2+plane)*4+ks)*512 + s8*64 + l
  __shared__ float red[4096];     // 16 KB: ((w4*2+m)*2+cg)*256 + l*4+r
  __shared__ float zg[1056];      // [b][c] stride 33

  const int tid = threadIdx.x;
  const int bx = blockIdx.x;
  const int l = tid & 63, w = tid >> 6;

  // --- stage U into LDS once (flat index == LDS layout index) ---
#pragma unroll
  for (int i = 0; i < 16; ++i) {
    int flat = i * 512 + tid;
    int ll = flat & 63, s8 = (flat >> 6) & 7, ks = (flat >> 9) & 3;
    int pl = (flat >> 11) & 1, cg = flat >> 12;
    size_t fi = (size_t)((bx * 2 + cg) * 4 + ks) * 8 + s8;
    UL[flat] = Ubf[fi * 128 + pl * 64 + ll];
  }

  // reducer mapping: tid -> (m = tid>>8, e = tid&255); 2 cols (cg 0,1) each
  const int e = tid & 255, m = tid >> 8;
  const int n16 = (e >> 2) & 15;
  const int zb = m * 16 + (e >> 6) * 4 + (e & 3);
  int zgcol[2];
#pragma unroll
  for (int cg = 0; cg < 2; ++cg)
    zgcol[cg] = (n16 & 3) * 1024 + (bx * 2 + cg) * 4 + (n16 >> 2);

  // gate mapping (tid<256): batch gb, unit gu (0..7); h-store word index
  const int gb = tid & 31, gu = tid >> 5;
  const int gk = bx * 8 + gu;
  const int widx = (gb >> 4) * 8192 + (gk >> 3) * 64 + (gb & 15) * 4 + ((gk & 7) >> 1);
  const int zrd = gb * 33 + (gu >> 2) * 16 + (gu & 3) * 4;
  float creg = 0.f;

  const int ks_w = w >> 1;                     // wave's kslice
  const unsigned* myflg = flg + (w * 16 + (l & 15)) * 32;   // 16 producers/wave

  __syncthreads();   // U staged

  for (int t = 0; t < S_; ++t) {
    const ull* RdH = (const ull*)((t & 1) ? Hh0 : Hh1);
    const ull* RdL = (const ull*)((t & 1) ? Hl0 : Hl1);
    unsigned* WrH = (t & 1) ? Hh1 : Hh0;
    unsigned* WrL = (t & 1) ? Hl1 : Hl0;

    // xz prefetch (independent of h)
    float xzv[2];
#pragma unroll
    for (int cg = 0; cg < 2; ++cg)
      xzv[cg] = __half2float(__ushort_as_half(xz[((size_t)t * G4_ + zgcol[cg]) * 32 + zb]));

    if (t > 0) {
      // per-wave poll of this wave's 16 producer blocks
      while (true) {
        unsigned v = __hip_atomic_load(myflg, __ATOMIC_RELAXED, __HIP_MEMORY_SCOPE_AGENT);
        if (__all((int)(v >= (unsigned)t))) break;
        __builtin_amdgcn_s_sleep(1);
      }

      // all A-fragment loads up-front: 4 k-steps x {m0h,m1h,m0l,m1l}
      union F { ull q[2]; bf16x8 v; };
      F A[4][4];
#pragma unroll
      for (int s = 0; s < 4; ++s) {
        int i0 = (w * 16 + s * 4) * 32 + l * 2;
        A[s][0].q[0] = ldq(RdH + i0);        A[s][0].q[1] = ldq(RdH + i0 + 1);
        A[s][1].q[0] = ldq(RdH + 4096 + i0); A[s][1].q[1] = ldq(RdH + 4096 + i0 + 1);
        A[s][2].q[0] = ldq(RdL + i0);        A[s][2].q[1] = ldq(RdL + i0 + 1);
        A[s][3].q[0] = ldq(RdL + 4096 + i0); A[s][3].q[1] = ldq(RdL + 4096 + i0 + 1);
      }

      f32x4 acc[2][2];
#pragma unroll
      for (int cg = 0; cg < 2; ++cg) {
        acc[cg][0] = (f32x4){0.f, 0.f, 0.f, 0.f};
        acc[cg][1] = (f32x4){0.f, 0.f, 0.f, 0.f};
      }
#pragma unroll
      for (int s = 0; s < 4; ++s) {
        int s8 = (w & 1) * 4 + s;
#pragma unroll
        for (int cg = 0; cg < 2; ++cg) {
          bf16x8 uhf = UL[((cg * 2 + 0) * 4 + ks_w) * 512 + s8 * 64 + l];
          bf16x8 ulf = UL[((cg * 2 + 1) * 4 + ks_w) * 512 + s8 * 64 + l];
          acc[cg][0] = __builtin_amdgcn_mfma_f32_16x16x32_bf16(A[s][0].v, uhf, acc[cg][0], 0, 0, 0);
          acc[cg][1] = __builtin_amdgcn_mfma_f32_16x16x32_bf16(A[s][1].v, uhf, acc[cg][1], 0, 0, 0);
          acc[cg][0] = __builtin_amdgcn_mfma_f32_16x16x32_bf16(A[s][2].v, uhf, acc[cg][0], 0, 0, 0);
          acc[cg][1] = __builtin_amdgcn_mfma_f32_16x16x32_bf16(A[s][3].v, uhf, acc[cg][1], 0, 0, 0);
          acc[cg][0] = __builtin_amdgcn_mfma_f32_16x16x32_bf16(A[s][0].v, ulf, acc[cg][0], 0, 0, 0);
          acc[cg][1] = __builtin_amdgcn_mfma_f32_16x16x32_bf16(A[s][1].v, ulf, acc[cg][1], 0, 0, 0);
        }
      }
      // two-pass reduction into 16 KB red
      if (w < 4) {
#pragma unroll
        for (int cg = 0; cg < 2; ++cg) {
          *(f32x4*)(&red[((w * 2 + 0) * 2 + cg) * 256 + l * 4]) = acc[cg][0];
          *(f32x4*)(&red[((w * 2 + 1) * 2 + cg) * 256 + l * 4]) = acc[cg][1];
        }
      }
      __syncthreads();
      if (w >= 4) {
        int w4 = w - 4;
#pragma unroll
        for (int cg = 0; cg < 2; ++cg) {
          f32x4* p0 = (f32x4*)(&red[((w4 * 2 + 0) * 2 + cg) * 256 + l * 4]);
          f32x4* p1 = (f32x4*)(&red[((w4 * 2 + 1) * 2 + cg) * 256 + l * 4]);
          *p0 += acc[cg][0];
          *p1 += acc[cg][1];
        }
      }
    }
    __syncthreads();

    // final reduce (4 slots) + xz -> zg
    {
      float z0 = xzv[0], z1 = xzv[1];
      if (t > 0) {
#pragma unroll
        for (int w4 = 0; w4 < 4; ++w4) {
          z0 += red[((w4 * 2 + m) * 2 + 0) * 256 + e];
          z1 += red[((w4 * 2 + m) * 2 + 1) * 256 + e];
        }
      }
      zg[zb * 33 + n16] = z0;
      zg[zb * 33 + 16 + n16] = z1;
    }
    __syncthreads();

    // gates: tid<256, one (b, unit) each
    if (tid < 256) {
      float zi = zg[zrd + 0];
      float zf = zg[zrd + 1];
      float zc_ = zg[zrd + 2];
      float zo = zg[zrd + 3];
      float ig = 1.f / (1.f + __expf(-zi));
      float fg = 1.f / (1.f + __expf(-zf));
      float gg = tanhf(zc_);
      float og = 1.f / (1.f + __expf(-zo));
      creg = fg * creg + ig * gg;
      float hv = og * tanhf(creg);
      unsigned short hh_ = f2bf(hv);
      unsigned short hl_ = f2bf(hv - bf2f(hh_));
      unsigned pk = (unsigned)hh_ | ((unsigned)hl_ << 16);
      unsigned other = (unsigned)__shfl_xor((int)pk, 32, 64);   // partner unit gu^1
      if ((gu & 1) == 0)
        stw(WrH + widx, (pk & 0xffffu) | (other << 16));
      else
        stw(WrL + widx, (other >> 16) | (pk & 0xffff0000u));
    }
    __syncthreads();   // drains all waves' vmcnt -> block's h slice at LLC
    if (tid == 0)
      stw(flg + bx * 32, (unsigned)(t + 1));
  }
}

// ---------------------------------------------------------------------------
// K3: logits from fragment-layout h. grid 5, block 256.
__global__ __launch_bounds__(256) void k_head4(const unsigned* __restrict__ Hh,
                                               const unsigned* __restrict__ Hl,
                                               const float* __restrict__ Wd,
                                               const float* __restrict__ bd,
                                               float* __restrict__ out) {
  __shared__ float red[32 * 9];
  int lbl = blockIdx.x;
  int tid = threadIdx.x;
  int b = tid >> 3, ks = tid & 7;
  int mb = (b >> 4) * 8192 + (b & 15) * 4;
  float acc = 0.f;
  for (int k = ks * 128; k < ks * 128 + 128; ++k) {
    int idx = mb + (k >> 3) * 64 + ((k & 7) >> 1);
    int sh = (k & 1) * 16;
    float hv = bf2f((unsigned short)((Hh[idx] >> sh) & 0xffffu)) +
               bf2f((unsigned short)((Hl[idx] >> sh) & 0xffffu));
    acc += hv * Wd[k * NL_ + lbl];
  }
  red[b * 9 + ks] = acc;
  __syncthreads();
  if (tid < 32) {
    float s = bd[lbl];
#pragma unroll
    for (int i = 0; i < 8; ++i) s += red[tid * 9 + i];
    out[tid * NL_ + lbl] = s;
  }
}

// ---------------------------------------------------------------------------
extern "C" void kernel_launch(void* const* d_in, const int* in_sizes, int n_in,
                              void* d_out, int out_size, void* d_ws, size_t ws_size,
                              hipStream_t stream) {
  const int* tokens  = (const int*)d_in[0];
  const float* emb   = (const float*)d_in[1];
  const float* W     = (const float*)d_in[2];
  const float* U     = (const float*)d_in[3];
  const float* bias  = (const float*)d_in[4];
  const float* Wd    = (const float*)d_in[5];
  const float* bd    = (const float*)d_in[6];
  float* out = (float*)d_out;

  char* ws = (char*)d_ws;
  // Overlaid layout:
  //   Ut fp32 [4096][1024]   @ 0          (16 MB, dead after k_prep)
  //   xz fp16 [256][4096][32] @ 0         (64 MB, written by k_xw after k_prep)
  //   Ubf bf16 frags         @ 67,108,864 (16 MB)
  //   frag-layout h planes: Hh0,Hl0,Hh1,Hl1 (64 KB each) @ 83,886,080
  //   flg                    @ 84,148,224 (16 KB: 128 flags, 128 B apart)
  float* Ut          = (float*)ws;
  unsigned short* xz = (unsigned short*)ws;
  bf16x8* Ubf        = (bf16x8*)(ws + 67108864);
  unsigned* Hh0      = (unsigned*)(ws + 83886080);
  unsigned* Hl0      = (unsigned*)(ws + 83886080 + 65536);
  unsigned* Hh1      = (unsigned*)(ws + 83886080 + 131072);
  unsigned* Hl1      = (unsigned*)(ws + 83886080 + 196608);
  unsigned* flg      = (unsigned*)(ws + 84148224);

  hipMemsetAsync(flg, 0, 16384, stream);
  k_transpose<<<dim3(128, 32), 256, 0, stream>>>(U, Ut);
  k_prep<<<2048, 256, 0, stream>>>(Ut, Ubf);
  k_xw<<<dim3(32, 256), 256, 0, stream>>>(tokens, emb, W, bias, xz);  // clobbers Ut (dead)

  k_steps5<<<NBLK, 512, 0, stream>>>(Ubf, xz, Hh0, Hl0, Hh1, Hl1, flg);

  // t=255 (odd) wrote buf1
  k_head4<<<NL_, 256, 0, stream>>>(Hh1, Hl1, Wd, bd, out);
}

// Round 9
// 1190.277 us; speedup vs baseline: 2.2730x; 1.4686x over previous
//
#include <hip/hip_runtime.h>
#include <hip/hip_fp16.h>

#define B_   32
#define S_   256
#define EMB_ 512
#define H_   1024
#define G4_  4096
#define NL_  5
#define NBLK 128

typedef short bf16x8 __attribute__((ext_vector_type(8)));
typedef _Float16 f16x8 __attribute__((ext_vector_type(8)));
typedef float f32x4 __attribute__((ext_vector_type(4)));
typedef unsigned long long ull;

__device__ inline unsigned short f2bf(float x) {
  unsigned u = __float_as_uint(x);
  return (unsigned short)((u + 0x7FFF + ((u >> 16) & 1)) >> 16);
}
__device__ inline float bf2f(unsigned short b) {
  return __uint_as_float(((unsigned)b) << 16);
}
__device__ inline ull ldq(const ull* p) {
  return __hip_atomic_load(p, __ATOMIC_RELAXED, __HIP_MEMORY_SCOPE_AGENT);
}
__device__ inline void stw(unsigned* p, unsigned v) {
  __hip_atomic_store(p, v, __ATOMIC_RELAXED, __HIP_MEMORY_SCOPE_AGENT);
}

// ---------------------------------------------------------------------------
// K0: transpose src [K][4096] -> dst [4096][K]. grid (128, K/32).
__global__ __launch_bounds__(256) void k_transposeK(const float* __restrict__ src,
                                                    float* __restrict__ dst, int K) {
  __shared__ float tile[32][33];
  int c0 = blockIdx.x * 32, k0 = blockIdx.y * 32;
  int tx = threadIdx.x & 31, ty = threadIdx.x >> 5;
#pragma unroll
  for (int i = 0; i < 4; ++i)
    tile[ty + 8 * i][tx] = src[(size_t)(k0 + ty + 8 * i) * G4_ + c0 + tx];
  __syncthreads();
#pragma unroll
  for (int i = 0; i < 4; ++i)
    dst[(size_t)(c0 + ty + 8 * i) * K + k0 + tx] = tile[tx][ty + 8 * i];
}

// ---------------------------------------------------------------------------
// K0b: U -> MFMA B-fragments, split bf16 hi/lo. (proven layout, unchanged)
// Ubf[((ug*4 + ks)*8 + s8)*128 + plane*64 + l]: value U[k][gcol],
// k = ks*256 + s8*32 + (l>>4)*8 + j, n16 = l&15,
// gcol = (n16&3)*1024 + ug*4 + (n16>>2).
__global__ __launch_bounds__(256) void k_prep(const float* __restrict__ Ut,
                                              bf16x8* __restrict__ Ubf) {
  int gid = blockIdx.x * 256 + threadIdx.x;
  int l = gid & 63;
  int bxws = gid >> 6;
  int n = l & 15, kgrp = l >> 4;
  int s = bxws & 7, bw = bxws >> 3;
  int w = bw & 3, bx = bw >> 2;
  int g = n & 3, ju = n >> 2;
  int gcol = g * 1024 + bx * 4 + ju;
  int kbase = w * 256 + s * 32 + kgrp * 8;
  const float4* f = (const float4*)(Ut + (size_t)gcol * H_ + kbase);
  float4 f0 = f[0], f1 = f[1];
  float v[8] = {f0.x, f0.y, f0.z, f0.w, f1.x, f1.y, f1.z, f1.w};
  bf16x8 vh, vl;
#pragma unroll
  for (int j = 0; j < 8; ++j) {
    unsigned short hi = f2bf(v[j]);
    vh[j] = (short)hi;
    vl[j] = (short)f2bf(v[j] - bf2f(hi));
  }
  Ubf[(size_t)bxws * 128 + l] = vh;
  Ubf[(size_t)bxws * 128 + 64 + l] = vl;
}

// ---------------------------------------------------------------------------
// K0c: W -> fp16 MFMA B-fragments (single plane).
// Wf16[(ug*16 + kc)*64 + l] (16B units): value fp16(W[k][gcol]),
// k = kc*32 + (l>>4)*8 + j, gcol = (n16&3)*1024 + ug*4 + (n16>>2), n16=l&15.
__global__ __launch_bounds__(256) void k_prepW16(const float* __restrict__ Wt,
                                                 unsigned short* __restrict__ Wf16) {
  int gid = blockIdx.x * 256 + threadIdx.x;   // 262144 total
  int l = gid & 63, fi = gid >> 6;
  int kc = fi & 15, ug = fi >> 4;
  int n16 = l & 15, kgrp = l >> 4;
  int gcol = (n16 & 3) * 1024 + ug * 4 + (n16 >> 2);
  const float4* f = (const float4*)(Wt + (size_t)gcol * 512 + kc * 32 + kgrp * 8);
  float4 f0 = f[0], f1 = f[1];
  float v[8] = {f0.x, f0.y, f0.z, f0.w, f1.x, f1.y, f1.z, f1.w};
  union { unsigned short u[8]; uint4 q; } o;
#pragma unroll
  for (int j = 0; j < 8; ++j) o.u[j] = __half_as_ushort(__float2half_rn(v[j]));
  *(uint4*)(Wf16 + ((size_t)fi * 64 + l) * 8) = o.q;
}

// ---------------------------------------------------------------------------
// K0d: gather emb rows -> Xf16 [256 s][32 b][512 e] fp16.
__global__ __launch_bounds__(256) void k_prepX(const int* __restrict__ tokens,
                                               const float* __restrict__ emb,
                                               unsigned short* __restrict__ Xf16) {
  int gid = blockIdx.x * 256 + threadIdx.x;   // 524288 total
  int seg = gid & 63, row = gid >> 6;
  int s = row >> 5, b = row & 31;
  int tok = tokens[b * 256 + s];
  const float4* f = (const float4*)(emb + (size_t)tok * EMB_ + seg * 8);
  float4 f0 = f[0], f1 = f[1];
  float v[8] = {f0.x, f0.y, f0.z, f0.w, f1.x, f1.y, f1.z, f1.w};
  union { unsigned short u[8]; uint4 q; } o;
#pragma unroll
  for (int j = 0; j < 8; ++j) o.u[j] = __half_as_ushort(__float2half_rn(v[j]));
  *(uint4*)(Xf16 + (size_t)row * 512 + seg * 8) = o.q;
}

// ---------------------------------------------------------------------------
// K2: persistent steps v6 = r8's v5 + fused xz (fp16 MFMA, no h dependency,
// runs before the flag poll) + fp32 bias in the reduce. grid 128 x 512.
// Block bx owns 8 units (32 gate cols); wave w = K-slice [w*128,(w+1)*128).
// U (bf16 hi/lo frags) staged in LDS once; W fp16 frags read from L2 (32 KB,
// same addrs every step -> cache-resident); x_t frags plain cached loads.
__global__ __launch_bounds__(512, 2) void k_steps6(
    const bf16x8* __restrict__ Ubf,
    const unsigned short* __restrict__ Wf16,
    const unsigned short* __restrict__ Xf16,
    const float* __restrict__ bias,
    unsigned* __restrict__ Hh0, unsigned* __restrict__ Hl0,
    unsigned* __restrict__ Hh1, unsigned* __restrict__ Hl1,
    unsigned* __restrict__ flg) {
  __shared__ bf16x8 UL[8192];     // 128 KB: ((cg*2+plane)*4+ks)*512 + s8*64 + l
  __shared__ float red[4096];     // 16 KB
  __shared__ float zg[1056];      // [b][c] stride 33
  __shared__ float bias_s[32];

  const int tid = threadIdx.x;
  const int bx = blockIdx.x;
  const int l = tid & 63, w = tid >> 6;

  // --- stage U into LDS once ---
#pragma unroll
  for (int i = 0; i < 16; ++i) {
    int flat = i * 512 + tid;
    int ll = flat & 63, s8 = (flat >> 6) & 7, ks = (flat >> 9) & 3;
    int pl = (flat >> 11) & 1, cg = flat >> 12;
    size_t fi = (size_t)((bx * 2 + cg) * 4 + ks) * 8 + s8;
    UL[flat] = Ubf[fi * 128 + pl * 64 + ll];
  }
  if (tid < 32) {
    int cg = tid >> 4, n16 = tid & 15;
    bias_s[tid] = bias[(n16 & 3) * 1024 + (bx * 2 + cg) * 4 + (n16 >> 2)];
  }

  // reducer mapping
  const int e = tid & 255, m = tid >> 8;
  const int n16r = (e >> 2) & 15;
  const int zb = m * 16 + (e >> 6) * 4 + (e & 3);

  // gate mapping (tid<256)
  const int gb = tid & 31, gu = tid >> 5;
  const int gk = bx * 8 + gu;
  const int widx = (gb >> 4) * 8192 + (gk >> 3) * 64 + (gb & 15) * 4 + ((gk & 7) >> 1);
  const int zrd = gb * 33 + (gu >> 2) * 16 + (gu & 3) * 4;
  float creg = 0.f;

  const int ks_w = w >> 1;
  const unsigned* myflg = flg + (w * 16 + (l & 15)) * 32;

  // per-wave xz fragment addresses (constant except t)
  const int xrow0 = (l & 15) * 512 + (l >> 4) * 8;

  __syncthreads();   // U staged

  for (int t = 0; t < S_; ++t) {
    const ull* RdH = (const ull*)((t & 1) ? Hh0 : Hh1);
    const ull* RdL = (const ull*)((t & 1) ? Hl0 : Hl1);
    unsigned* WrH = (t & 1) ? Hh1 : Hh0;
    unsigned* WrL = (t & 1) ? Hl1 : Hl0;

    // ---- xz part: acc = x_t @ W (fp16 MFMA), no h dependency ----
    f32x4 acc[2][2];
#pragma unroll
    for (int cg = 0; cg < 2; ++cg) {
      acc[cg][0] = (f32x4){0.f, 0.f, 0.f, 0.f};
      acc[cg][1] = (f32x4){0.f, 0.f, 0.f, 0.f};
    }
    {
      const unsigned short* Xt = Xf16 + (size_t)t * 16384;
#pragma unroll
      for (int c2 = 0; c2 < 2; ++c2) {
        int kc = w * 2 + c2;
        f16x8 xa0 = *(const f16x8*)(Xt + xrow0 + kc * 32);
        f16x8 xa1 = *(const f16x8*)(Xt + 8192 + xrow0 + kc * 32);
        f16x8 wb0 = *(const f16x8*)(Wf16 + ((size_t)((bx * 2 + 0) * 16 + kc) * 64 + l) * 8);
        f16x8 wb1 = *(const f16x8*)(Wf16 + ((size_t)((bx * 2 + 1) * 16 + kc) * 64 + l) * 8);
        acc[0][0] = __builtin_amdgcn_mfma_f32_16x16x32_f16(xa0, wb0, acc[0][0], 0, 0, 0);
        acc[0][1] = __builtin_amdgcn_mfma_f32_16x16x32_f16(xa1, wb0, acc[0][1], 0, 0, 0);
        acc[1][0] = __builtin_amdgcn_mfma_f32_16x16x32_f16(xa0, wb1, acc[1][0], 0, 0, 0);
        acc[1][1] = __builtin_amdgcn_mfma_f32_16x16x32_f16(xa1, wb1, acc[1][1], 0, 0, 0);
      }
    }

    // ---- recurrence part ----
    if (t > 0) {
      while (true) {
        unsigned v = __hip_atomic_load(myflg, __ATOMIC_RELAXED, __HIP_MEMORY_SCOPE_AGENT);
        if (__all((int)(v >= (unsigned)t))) break;
        __builtin_amdgcn_s_sleep(1);
      }
      union F { ull q[2]; bf16x8 v; };
      F A[4][4];
#pragma unroll
      for (int s = 0; s < 4; ++s) {
        int i0 = (w * 16 + s * 4) * 32 + l * 2;
        A[s][0].q[0] = ldq(RdH + i0);        A[s][0].q[1] = ldq(RdH + i0 + 1);
        A[s][1].q[0] = ldq(RdH + 4096 + i0); A[s][1].q[1] = ldq(RdH + 4096 + i0 + 1);
        A[s][2].q[0] = ldq(RdL + i0);        A[s][2].q[1] = ldq(RdL + i0 + 1);
        A[s][3].q[0] = ldq(RdL + 4096 + i0); A[s][3].q[1] = ldq(RdL + 4096 + i0 + 1);
      }
#pragma unroll
      for (int s = 0; s < 4; ++s) {
        int s8 = (w & 1) * 4 + s;
#pragma unroll
        for (int cg = 0; cg < 2; ++cg) {
          bf16x8 uhf = UL[((cg * 2 + 0) * 4 + ks_w) * 512 + s8 * 64 + l];
          bf16x8 ulf = UL[((cg * 2 + 1) * 4 + ks_w) * 512 + s8 * 64 + l];
          acc[cg][0] = __builtin_amdgcn_mfma_f32_16x16x32_bf16(A[s][0].v, uhf, acc[cg][0], 0, 0, 0);
          acc[cg][1] = __builtin_amdgcn_mfma_f32_16x16x32_bf16(A[s][1].v, uhf, acc[cg][1], 0, 0, 0);
          acc[cg][0] = __builtin_amdgcn_mfma_f32_16x16x32_bf16(A[s][2].v, uhf, acc[cg][0], 0, 0, 0);
          acc[cg][1] = __builtin_amdgcn_mfma_f32_16x16x32_bf16(A[s][3].v, uhf, acc[cg][1], 0, 0, 0);
          acc[cg][0] = __builtin_amdgcn_mfma_f32_16x16x32_bf16(A[s][0].v, ulf, acc[cg][0], 0, 0, 0);
          acc[cg][1] = __builtin_amdgcn_mfma_f32_16x16x32_bf16(A[s][1].v, ulf, acc[cg][1], 0, 0, 0);
        }
      }
    }

    // ---- two-pass reduction (always) ----
    if (w < 4) {
#pragma unroll
      for (int cg = 0; cg < 2; ++cg) {
        *(f32x4*)(&red[((w * 2 + 0) * 2 + cg) * 256 + l * 4]) = acc[cg][0];
        *(f32x4*)(&red[((w * 2 + 1) * 2 + cg) * 256 + l * 4]) = acc[cg][1];
      }
    }
    __syncthreads();
    if (w >= 4) {
      int w4 = w - 4;
#pragma unroll
      for (int cg = 0; cg < 2; ++cg) {
        f32x4* p0 = (f32x4*)(&red[((w4 * 2 + 0) * 2 + cg) * 256 + l * 4]);
        f32x4* p1 = (f32x4*)(&red[((w4 * 2 + 1) * 2 + cg) * 256 + l * 4]);
        *p0 += acc[cg][0];
        *p1 += acc[cg][1];
      }
    }
    __syncthreads();

    // ---- final reduce + fp32 bias -> zg ----
    {
      float z0 = bias_s[n16r], z1 = bias_s[16 + n16r];
#pragma unroll
      for (int w4 = 0; w4 < 4; ++w4) {
        z0 += red[((w4 * 2 + m) * 2 + 0) * 256 + e];
        z1 += red[((w4 * 2 + m) * 2 + 1) * 256 + e];
      }
      zg[zb * 33 + n16r] = z0;
      zg[zb * 33 + 16 + n16r] = z1;
    }
    __syncthreads();

    // ---- gates ----
    if (tid < 256) {
      float zi = zg[zrd + 0];
      float zf = zg[zrd + 1];
      float zc_ = zg[zrd + 2];
      float zo = zg[zrd + 3];
      float ig = 1.f / (1.f + __expf(-zi));
      float fg = 1.f / (1.f + __expf(-zf));
      float gg = tanhf(zc_);
      float og = 1.f / (1.f + __expf(-zo));
      creg = fg * creg + ig * gg;
      float hv = og * tanhf(creg);
      unsigned short hh_ = f2bf(hv);
      unsigned short hl_ = f2bf(hv - bf2f(hh_));
      unsigned pk = (unsigned)hh_ | ((unsigned)hl_ << 16);
      unsigned other = (unsigned)__shfl_xor((int)pk, 32, 64);   // partner unit gu^1
      if ((gu & 1) == 0)
        stw(WrH + widx, (pk & 0xffffu) | (other << 16));
      else
        stw(WrL + widx, (other >> 16) | (pk & 0xffff0000u));
    }
    __syncthreads();   // drains all waves' vmcnt -> block's h slice at LLC
    if (tid == 0)
      stw(flg + bx * 32, (unsigned)(t + 1));
  }
}

// ---------------------------------------------------------------------------
// K3: logits from fragment-layout h. grid 5, block 256.
__global__ __launch_bounds__(256) void k_head4(const unsigned* __restrict__ Hh,
                                               const unsigned* __restrict__ Hl,
                                               const float* __restrict__ Wd,
                                               const float* __restrict__ bd,
                                               float* __restrict__ out) {
  __shared__ float red[32 * 9];
  int lbl = blockIdx.x;
  int tid = threadIdx.x;
  int b = tid >> 3, ks = tid & 7;
  int mb = (b >> 4) * 8192 + (b & 15) * 4;
  float acc = 0.f;
  for (int k = ks * 128; k < ks * 128 + 128; ++k) {
    int idx = mb + (k >> 3) * 64 + ((k & 7) >> 1);
    int sh = (k & 1) * 16;
    float hv = bf2f((unsigned short)((Hh[idx] >> sh) & 0xffffu)) +
               bf2f((unsigned short)((Hl[idx] >> sh) & 0xffffu));
    acc += hv * Wd[k * NL_ + lbl];
  }
  red[b * 9 + ks] = acc;
  __syncthreads();
  if (tid < 32) {
    float s = bd[lbl];
#pragma unroll
    for (int i = 0; i < 8; ++i) s += red[tid * 9 + i];
    out[tid * NL_ + lbl] = s;
  }
}

// ---------------------------------------------------------------------------
extern "C" void kernel_launch(void* const* d_in, const int* in_sizes, int n_in,
                              void* d_out, int out_size, void* d_ws, size_t ws_size,
                              hipStream_t stream) {
  const int* tokens  = (const int*)d_in[0];
  const float* emb   = (const float*)d_in[1];
  const float* W     = (const float*)d_in[2];
  const float* U     = (const float*)d_in[3];
  const float* bias  = (const float*)d_in[4];
  const float* Wd    = (const float*)d_in[5];
  const float* bd    = (const float*)d_in[6];
  float* out = (float*)d_out;

  char* ws = (char*)d_ws;
  // Layout (max 84,164,608 B — within proven budget):
  //   Xf16 fp16 [256][32][512]  @ 0           (8 MiB)
  //   Wf16 fp16 frags           @ 8,388,608   (4 MiB)
  //   Ut fp32 (transient)       @ 16,777,216  (16 MiB)
  //   Wt fp32 (transient)       @ 33,554,432  (8 MiB)
  //   Ubf bf16 frags            @ 67,108,864  (16 MiB)
  //   h planes Hh0,Hl0,Hh1,Hl1  @ 83,886,080  (4 x 64 KB)
  //   flg                       @ 84,148,224  (16 KB)
  unsigned short* Xf16 = (unsigned short*)ws;
  unsigned short* Wf16 = (unsigned short*)(ws + 8388608);
  float* Ut          = (float*)(ws + 16777216);
  float* Wt          = (float*)(ws + 33554432);
  bf16x8* Ubf        = (bf16x8*)(ws + 67108864);
  unsigned* Hh0      = (unsigned*)(ws + 83886080);
  unsigned* Hl0      = (unsigned*)(ws + 83886080 + 65536);
  unsigned* Hh1      = (unsigned*)(ws + 83886080 + 131072);
  unsigned* Hl1      = (unsigned*)(ws + 83886080 + 196608);
  unsigned* flg      = (unsigned*)(ws + 84148224);

  hipMemsetAsync(flg, 0, 16384, stream);
  k_transposeK<<<dim3(128, 32), 256, 0, stream>>>(U, Ut, 1024);
  k_prep<<<2048, 256, 0, stream>>>(Ut, Ubf);
  k_transposeK<<<dim3(128, 16), 256, 0, stream>>>(W, Wt, 512);
  k_prepW16<<<1024, 256, 0, stream>>>(Wt, Wf16);
  k_prepX<<<2048, 256, 0, stream>>>(tokens, emb, Xf16);

  k_steps6<<<NBLK, 512, 0, stream>>>(Ubf, Wf16, Xf16, bias,
                                     Hh0, Hl0, Hh1, Hl1, flg);

  // t=255 (odd) wrote buf1
  k_head4<<<NL_, 256, 0, stream>>>(Hh1, Hl1, Wd, bd, out);
}